// Round 4
// baseline (672.075 us; speedup 1.0000x reference)
//
#include <hip/hip_runtime.h>
#include <math.h>

// Problem constants (from reference): B=8, S=8192, D=1024, keep_ratio=0.5
#define BB 8
#define SS 8192
#define DD 1024
#define NTOK (BB * SS)                 // 65536 tokens
#define NWAVES 8192                    // total score waves
#define TOK_PER_WAVE (NTOK / NWAVES)   // 8
#define WPB 16                         // waves per block (1024 threads)
#define GRID (NWAVES / WPB)            // 512 blocks

__device__ __forceinline__ float dot4(float4 a, float4 b) {
    return a.x * b.x + a.y * b.y + a.z * b.z + a.w * b.w;
}

// ---------------------------------------------------------------------------
// Fused kernel: all 512 blocks score (8 tokens/wave, w cached in 16 VGPRs,
// zero barriers in the hot loop). Each block then release-fences and bumps a
// device counter; blocks 0..7 acquire-spin until all 512 blocks are done,
// then run the per-row radix top-k select and overwrite buf with int32 0/1.
// ---------------------------------------------------------------------------
__global__ __launch_bounds__(1024) void fused_kernel(
    const float* __restrict__ hs, const int* __restrict__ mask,
    const float* __restrict__ w, const float* __restrict__ bias,
    float* __restrict__ buf, unsigned int* __restrict__ done)
{
    __shared__ unsigned int keys[SS];          // 32 KB (select phase only)
    __shared__ unsigned int hist[256];
    __shared__ unsigned int wsum[WPB];
    __shared__ unsigned int n_active_sh, sel_bin, sel_knew;

    const int tid  = threadIdx.x;
    const int widx = tid >> 6;
    const int lane = tid & 63;
    const int gw   = blockIdx.x * WPB + widx;  // global wave id, 0..8191

    // ---------------- score phase ----------------
    const float4* wp = (const float4*)w;
    const float4 w0 = wp[lane];
    const float4 w1 = wp[lane + 64];
    const float4 w2 = wp[lane + 128];
    const float4 w3 = wp[lane + 192];
    const float b = bias[0];

#pragma unroll
    for (int t = 0; t < TOK_PER_WAVE; t += 2) {
        const int tokA = t * NWAVES + gw;
        const int tokB = (t + 1) * NWAVES + gw;
        const float4* hA = (const float4*)(hs + (size_t)tokA * DD);
        const float4* hB = (const float4*)(hs + (size_t)tokB * DD);

        // 8 float4 loads in flight per wave before first use
        float4 a0 = hA[lane];       float4 a1 = hA[lane + 64];
        float4 a2 = hA[lane + 128]; float4 a3 = hA[lane + 192];
        float4 c0 = hB[lane];       float4 c1 = hB[lane + 64];
        float4 c2 = hB[lane + 128]; float4 c3 = hB[lane + 192];

        float sA = dot4(a0, w0) + dot4(a1, w1) + dot4(a2, w2) + dot4(a3, w3);
        float sB = dot4(c0, w0) + dot4(c1, w1) + dot4(c2, w2) + dot4(c3, w3);

#pragma unroll
        for (int off = 32; off > 0; off >>= 1) {
            sA += __shfl_down(sA, off, 64);
            sB += __shfl_down(sB, off, 64);
        }
        if (lane == 0) {
            buf[tokA] = (mask[tokA] != 0) ? (sA + b) : -INFINITY;
            buf[tokB] = (mask[tokB] != 0) ? (sB + b) : -INFINITY;
        }
    }

    // Release: make this block's score stores device-visible, then count in.
    __threadfence();
    __syncthreads();
    if (tid == 0) atomicAdd(done, 1u);

    if (blockIdx.x >= BB) return;

    // ---------------- select phase (blocks 0..7) ----------------
    const int row = blockIdx.x;
    if (tid == 0) {
        while (atomicAdd(done, 0u) < (unsigned int)GRID)
            __builtin_amdgcn_s_sleep(2);
        n_active_sh = 0;
    }
    __syncthreads();
    __threadfence();   // acquire: invalidate stale cached lines of buf

    const float* srow = buf + row * SS;
    const int* mrow = mask + row * SS;

    unsigned int mycnt = 0;
    for (int i = tid; i < SS; i += 1024) {
        unsigned int u = __float_as_uint(srow[i]);
        keys[i] = (u & 0x80000000u) ? ~u : (u | 0x80000000u);
        if (mrow[i] != 0) mycnt++;
    }
    atomicAdd(&n_active_sh, mycnt);
    __syncthreads();

    const unsigned int n_active = n_active_sh;
    unsigned int k = (n_active + 1u) >> 1;     // ceil(n*0.5)
    if (k < 1u) k = 1u;

    // 4-round MSB-first radix select for the k-th largest key.
    unsigned int prefix = 0, prefmask = 0;
    for (int round = 0; round < 4; ++round) {
        const int shift = 24 - 8 * round;
        if (tid < 256) hist[tid] = 0;
        __syncthreads();
        for (int i = tid; i < SS; i += 1024) {
            unsigned int key = keys[i];
            if ((key & prefmask) == prefix)
                atomicAdd(&hist[(key >> shift) & 0xFFu], 1u);
        }
        __syncthreads();
        // Wave 0: suffix scan over 256 bins, 4 bins/lane, barrier-free.
        if (tid < 64) {
            const int ln = tid;
            unsigned int h0 = hist[4 * ln];
            unsigned int h1 = hist[4 * ln + 1];
            unsigned int h2 = hist[4 * ln + 2];
            unsigned int h3 = hist[4 * ln + 3];
            unsigned int local = h0 + h1 + h2 + h3;
            unsigned int suf = local;
#pragma unroll
            for (int off = 1; off < 64; off <<= 1) {
                unsigned int v = (unsigned int)__shfl_down((int)suf, off, 64);
                if (ln + off < 64) suf += v;
            }
            unsigned int above = suf - local;   // sum over lanes > ln
            unsigned int s3 = h3 + above;
            unsigned int s2 = h2 + s3;
            unsigned int s1 = h1 + s2;
            unsigned int s0 = h0 + s1;
            if (s3 >= k && above < k) { sel_bin = 4u*ln + 3u; sel_knew = k - above; }
            if (s2 >= k && s3    < k) { sel_bin = 4u*ln + 2u; sel_knew = k - s3; }
            if (s1 >= k && s2    < k) { sel_bin = 4u*ln + 1u; sel_knew = k - s2; }
            if (s0 >= k && s1    < k) { sel_bin = 4u*ln;      sel_knew = k - s1; }
        }
        __syncthreads();
        prefix |= sel_bin << shift;
        prefmask |= 0xFFu << shift;
        k = sel_knew;
        __syncthreads();
    }

    const unsigned int thr = prefix;   // exact key of k-th largest
    const unsigned int k_rem = k;      // how many ==thr to keep (lowest index)

    // Stable tie ranking: contiguous 8-element chunk per thread, block scan.
    const int base = tid * 8;
    unsigned int cnt = 0;
#pragma unroll
    for (int j = 0; j < 8; ++j) cnt += (keys[base + j] == thr) ? 1u : 0u;

    unsigned int inc = cnt;
#pragma unroll
    for (int off = 1; off < 64; off <<= 1) {
        unsigned int n = (unsigned int)__shfl_up((int)inc, off, 64);
        if (lane >= off) inc += n;
    }
    if (lane == 63) wsum[widx] = inc;
    __syncthreads();
    if (tid == 0) {
        unsigned int acc = 0;
        for (int i = 0; i < WPB; ++i) { unsigned int t = wsum[i]; wsum[i] = acc; acc += t; }
    }
    __syncthreads();
    unsigned int r = wsum[widx] + inc - cnt;   // exclusive rank among ==thr

    // Overwrite buf row with int32 keep mask (reference output bool->int32)
    int* orow = (int*)(buf + row * SS);
#pragma unroll
    for (int j = 0; j < 8; ++j) {
        const int i = base + j;
        const unsigned int key = keys[i];
        bool keep;
        if (key > thr) keep = true;
        else if (key == thr) { keep = (r < k_rem); r++; }
        else keep = false;
        keep = keep && (mrow[i] != 0);
        orow[i] = keep ? 1 : 0;
    }
}

extern "C" void kernel_launch(void* const* d_in, const int* in_sizes, int n_in,
                              void* d_out, int out_size, void* d_ws, size_t ws_size,
                              hipStream_t stream) {
    const float* hs   = (const float*)d_in[0];   // [B,S,D] fp32
    const int* msk    = (const int*)d_in[1];     // [B,S] int32 0/1 (bool)
    const float* w    = (const float*)d_in[2];   // [D]
    const float* bias = (const float*)d_in[3];   // [1]

    float* buf = (float*)d_out;                  // scores staged, then int mask
    unsigned int* done = (unsigned int*)d_ws;    // 1 counter, zeroed each call

    hipMemsetAsync(d_ws, 0, 64, stream);         // capturable memset node
    fused_kernel<<<GRID, 1024, 0, stream>>>(hs, msk, w, bias, buf, done);
}

// Round 5
// 372.421 us; speedup vs baseline: 1.8046x; 1.8046x over previous
//
#include <hip/hip_runtime.h>
#include <math.h>

// Problem constants (from reference): B=8, S=8192, D=1024, keep_ratio=0.5
#define BB 8
#define SS 8192
#define DD 1024
#define NTOK (BB * SS)          // 65536 tokens
#define NWAVES 8192             // 2048 blocks x 4 waves
#define TOK_PER_WAVE (NTOK / NWAVES)   // 8

__device__ __forceinline__ float dot4(float4 a, float4 b) {
    return a.x * b.x + a.y * b.y + a.z * b.z + a.w * b.w;
}

// ---------------------------------------------------------------------------
// Kernel 1 (unchanged from R3): scores = dot(hidden, w) + b, -inf if inactive.
// 8192 waves; 8 tokens/wave, 2 at a time; w cached in 16 VGPRs per lane.
// Own kernel => compiler free to hold 8 float4 loads in flight (R4 showed
// fusing with the 1024-thread select collapsed VGPRs to 36 and serialized).
// ---------------------------------------------------------------------------
__global__ __launch_bounds__(256) void score_kernel(
    const float* __restrict__ hs, const int* __restrict__ mask,
    const float* __restrict__ w, const float* __restrict__ bias,
    float* __restrict__ scores)
{
    const int gw   = blockIdx.x * 4 + (threadIdx.x >> 6);  // global wave id
    const int lane = threadIdx.x & 63;

    const float4* wp = (const float4*)w;
    const float4 w0 = wp[lane];
    const float4 w1 = wp[lane + 64];
    const float4 w2 = wp[lane + 128];
    const float4 w3 = wp[lane + 192];
    const float b = bias[0];

#pragma unroll
    for (int t = 0; t < TOK_PER_WAVE; t += 2) {
        const int tokA = t * NWAVES + gw;
        const int tokB = (t + 1) * NWAVES + gw;
        const float4* hA = (const float4*)(hs + (size_t)tokA * DD);
        const float4* hB = (const float4*)(hs + (size_t)tokB * DD);

        float4 a0 = hA[lane];       float4 a1 = hA[lane + 64];
        float4 a2 = hA[lane + 128]; float4 a3 = hA[lane + 192];
        float4 c0 = hB[lane];       float4 c1 = hB[lane + 64];
        float4 c2 = hB[lane + 128]; float4 c3 = hB[lane + 192];

        float sA = dot4(a0, w0) + dot4(a1, w1) + dot4(a2, w2) + dot4(a3, w3);
        float sB = dot4(c0, w0) + dot4(c1, w1) + dot4(c2, w2) + dot4(c3, w3);

#pragma unroll
        for (int off = 32; off > 0; off >>= 1) {
            sA += __shfl_down(sA, off, 64);
            sB += __shfl_down(sB, off, 64);
        }
        if (lane == 0) {
            scores[tokA] = (mask[tokA] != 0) ? (sA + b) : -INFINITY;
            scores[tokB] = (mask[tokB] != 0) ? (sB + b) : -INFINITY;
        }
    }
}

// ---------------------------------------------------------------------------
// Kernel 2: per-row top-k, 3-round radix select (11/11/10 bits => 2048-bin
// round 0 spreads LDS-atomic contention vs 256-bin), stable ties by index.
// One 1024-thread block per row; overwrites buf in-place with int32 0/1.
// ---------------------------------------------------------------------------
__global__ __launch_bounds__(1024) void select_kernel(
    const int* __restrict__ mask, float* __restrict__ buf)
{
    __shared__ unsigned int keys[SS];          // 32 KB
    __shared__ unsigned int hist[2048];        // 8 KB
    __shared__ unsigned int wred[16];
    __shared__ unsigned int n_active_sh, sel_bin, sel_knew;

    const int row = blockIdx.x;
    const int tid = threadIdx.x;
    const int lane = tid & 63, wv = tid >> 6;
    const float* srow = buf + row * SS;
    const int* mrow = mask + row * SS;

    // Stage keys (order-preserving float->uint) + count active via shfl.
    unsigned int mycnt = 0;
    for (int i = tid; i < SS; i += 1024) {
        unsigned int u = __float_as_uint(srow[i]);
        keys[i] = (u & 0x80000000u) ? ~u : (u | 0x80000000u);
        mycnt += (mrow[i] != 0) ? 1u : 0u;
    }
#pragma unroll
    for (int off = 32; off > 0; off >>= 1)
        mycnt += (unsigned int)__shfl_down((int)mycnt, off, 64);
    if (lane == 0) wred[wv] = mycnt;
    __syncthreads();
    if (tid == 0) {
        unsigned int s = 0;
        for (int i = 0; i < 16; ++i) s += wred[i];
        n_active_sh = s;
    }
    __syncthreads();

    const unsigned int n_active = n_active_sh;
    unsigned int k = (n_active + 1u) >> 1;     // ceil(n*0.5)
    if (k < 1u) k = 1u;

    // 3-round MSB-first radix select: bit fields [31:21], [20:10], [9:0].
    unsigned int prefix = 0, prefmask = 0;
    const int shifts_[3] = {21, 10, 0};
    const int nbins_[3] = {2048, 2048, 1024};
    for (int round = 0; round < 3; ++round) {
        const int shift = shifts_[round];
        const unsigned int NB = (unsigned int)nbins_[round];
        const unsigned int dmask = NB - 1u;

        for (int b2 = tid; b2 < (int)NB; b2 += 1024) hist[b2] = 0;
        __syncthreads();
        for (int i = tid; i < SS; i += 1024) {
            unsigned int key = keys[i];
            if ((key & prefmask) == prefix)
                atomicAdd(&hist[(key >> shift) & dmask], 1u);
        }
        __syncthreads();
        // Wave 0: suffix scan over NB bins, NB/64 bins/lane, barrier-free.
        if (tid < 64) {
            const int ln = tid;
            const int bpl = (int)NB / 64;          // 32 or 16
            unsigned int local = 0;
            for (int j = 0; j < bpl; ++j) local += hist[ln * bpl + j];
            unsigned int suf = local;
#pragma unroll
            for (int off = 1; off < 64; off <<= 1) {
                unsigned int v = (unsigned int)__shfl_down((int)suf, off, 64);
                if (ln + off < 64) suf += v;
            }
            unsigned int run = suf - local;        // count in lanes > ln
            for (int j = bpl - 1; j >= 0; --j) {   // descending bins in lane
                unsigned int hv = hist[ln * bpl + j];
                unsigned int s = hv + run;         // suffix(bin j)
                if (s >= k && run < k) {           // unique crossing bin
                    sel_bin = (unsigned int)(ln * bpl + j);
                    sel_knew = k - run;
                }
                run = s;
            }
        }
        __syncthreads();
        prefix |= sel_bin << shift;
        prefmask |= dmask << shift;
        k = sel_knew;
        __syncthreads();
    }

    const unsigned int thr = prefix;   // exact key of k-th largest
    const unsigned int k_rem = k;      // how many ==thr to keep (lowest index)

    // Stable tie ranking: contiguous 8-element chunk per thread, block scan.
    const int base = tid * 8;
    unsigned int cnt = 0;
#pragma unroll
    for (int j = 0; j < 8; ++j) cnt += (keys[base + j] == thr) ? 1u : 0u;

    unsigned int inc = cnt;
#pragma unroll
    for (int off = 1; off < 64; off <<= 1) {
        unsigned int n = (unsigned int)__shfl_up((int)inc, off, 64);
        if (lane >= off) inc += n;
    }
    if (lane == 63) wred[wv] = inc;
    __syncthreads();
    if (tid == 0) {
        unsigned int acc = 0;
        for (int i = 0; i < 16; ++i) { unsigned int t = wred[i]; wred[i] = acc; acc += t; }
    }
    __syncthreads();
    unsigned int r = wred[wv] + inc - cnt;   // exclusive rank among ==thr

    // Overwrite buf row with int32 keep mask (reference output bool->int32)
    int* orow = (int*)(buf + row * SS);
#pragma unroll
    for (int j = 0; j < 8; ++j) {
        const int i = base + j;
        const unsigned int key = keys[i];
        bool keep;
        if (key > thr) keep = true;
        else if (key == thr) { keep = (r < k_rem); r++; }
        else keep = false;
        keep = keep && (mrow[i] != 0);
        orow[i] = keep ? 1 : 0;
    }
}

extern "C" void kernel_launch(void* const* d_in, const int* in_sizes, int n_in,
                              void* d_out, int out_size, void* d_ws, size_t ws_size,
                              hipStream_t stream) {
    const float* hs   = (const float*)d_in[0];   // [B,S,D] fp32
    const int* msk    = (const int*)d_in[1];     // [B,S] int32 0/1 (bool)
    const float* w    = (const float*)d_in[2];   // [D]
    const float* bias = (const float*)d_in[3];   // [1]

    // Stage fp32 scores in d_out, then overwrite in-place with int32 mask.
    float* buf = (float*)d_out;                  // B*S elements = 256 KB

    score_kernel<<<NWAVES / 4, 256, 0, stream>>>(hs, msk, w, bias, buf);
    select_kernel<<<BB, 1024, 0, stream>>>(msk, buf);
}